// Round 4
// baseline (207.840 us; speedup 1.0000x reference)
//
#include <hip/hip_runtime.h>
#include <stdint.h>

typedef unsigned int u32;
typedef unsigned long long u64;

#define N_ITEMS 131072
#define NB 131072                   // buckets (monotone in descending score)
#define MBLK 64                     // solver blocks
#define NBLK 512                    // total blocks in kernels A/B
#define BUCK_PER_BLK 2048           // buckets per solver block
#define CH_PER_BLK 32               // chunks (64 buckets) per solver block
#define PAD 65                      // padded LDS record stride per chunk
#define REGSLOT 2048                // record slots per region in global REC
#define FPAD 16                     // u64s per flag slot -> 128B (own cacheline)
#define FIXSCALE 268435456.0f       // 2^28 fixed-point scale for sum(exp)
#define FIXMASK ((1ull << 46) - 1)

// ---------- helpers ----------

// sum_{i=s}^{e} (N - i) — exact weight-side sum of exp(w) over sorted positions
__device__ __forceinline__ float wsumf(int s, int e) {
  return 0.5f * (float)(e - s + 1) * (float)(2 * N_ITEMS - s - e);
}

__device__ __forceinline__ float key_to_score(u32 key) {
  u32 m = ~key;
  u32 u = (m & 0x80000000u) ? (m ^ 0x80000000u) : ~m;
  return __uint_as_float(u);
}

#define LOG2E 1.4426950408889634f
__device__ __forceinline__ float fexp(float x) { return exp2f(x * LOG2E); }

// ascending key == descending score; ascending bucket == descending score
__device__ __forceinline__ u32 bucket_of(u32 key, u32 kmin, u32 kmax) {
  double scale = (double)NB / ((double)(kmax - kmin) + 1.0);
  u32 b = (u32)((double)(key - kmin) * scale);
  return b < NB ? b : (NB - 1);
}

__device__ __forceinline__ float recSY(int2 r) { return __int_as_float(r.y); }

// relaxed agent-scope load: polls WITHOUT taking exclusive line ownership
__device__ __forceinline__ u64 agent_ld(const u64* p) {
  return __hip_atomic_load(p, __ATOMIC_RELAXED, __HIP_MEMORY_SCOPE_AGENT);
}

// ---------- 1) fused: scores -> keys -> minmax atomics -> grid barrier -> hist ----------
// 512 blocks x 256, tiny LDS/VGPR -> 8 blocks/CU capacity: all co-resident, barrier safe.
// Arrivals are per-block padded STORES (no shared-line RMW); block 0 load-polls then releases.

__global__ __launch_bounds__(256) void score_hist_kernel(
    const float* __restrict__ x,
    const float* __restrict__ w1, const float* __restrict__ b1,
    const float* __restrict__ w2, const float* __restrict__ b2,
    u32* __restrict__ keyRaw, u32* __restrict__ agg, u64* __restrict__ hist,
    u64* __restrict__ bar, u64* __restrict__ rel) {
  __shared__ u32 wmn[4], wmx[4];
  int t = threadIdx.x;
  int i = blockIdx.x * 256 + t;
  // zero the 1 MB histogram (one uint2 per thread, coalesced)
  ((uint2*)hist)[i] = make_uint2(0u, 0u);
  float xv = x[i];
  float s = b2[0];
#pragma unroll
  for (int j = 0; j < 32; ++j) {
    float h = fmaf(xv, w1[j], b1[j]);
    h = fmaxf(h, 0.0f);
    s = fmaf(h, w2[j], s);
  }
  u32 u = __float_as_uint(s);
  u32 mb = u ^ ((u & 0x80000000u) ? 0xFFFFFFFFu : 0x80000000u); // ascending map
  u32 key = ~mb;
  keyRaw[i] = key;
  u32 mn = key, mx = key;
#pragma unroll
  for (int off = 32; off > 0; off >>= 1) {
    mn = min(mn, (u32)__shfl_xor((int)mn, off));
    mx = max(mx, (u32)__shfl_xor((int)mx, off));
  }
  if ((t & 63) == 0) { wmn[t >> 6] = mn; wmx[t >> 6] = mx; }
  __syncthreads();                       // also drains hist-zero stores to L2
  if (t == 0) {
    mn = min(min(wmn[0], wmn[1]), min(wmn[2], wmn[3]));
    mx = max(max(wmx[0], wmx[1]), max(wmx[2], wmx[3]));
    atomicMax(&agg[0], ~mn);
    atomicMax(&agg[1], mx);
    __threadfence();                     // release: L2 writeback (zeros + partial minmax)
    atomicExch(&bar[(size_t)blockIdx.x * FPAD], 1ull);  // arrive (own line)
  }
  if (blockIdx.x == 0) {
    u64 f;
    do { f = agent_ld(&bar[(size_t)t * FPAD]); } while (f == 0ull);
    do { f = agent_ld(&bar[(size_t)(t + 256) * FPAD]); } while (f == 0ull);
    __syncthreads();
    if (t == 0) { __threadfence(); atomicExch(rel, 1ull); }
  } else {
    if (t == 0) {
      u64 f;
      do { f = agent_ld(rel); __builtin_amdgcn_s_sleep(1); } while (f == 0ull);
    }
    __syncthreads();
  }
  __threadfence();                       // acquire: invalidate stale copies
  u32 kmin = ~agg[0], kmax = agg[1];
  u32 g = bucket_of(key, kmin, kmax);
  float smax = key_to_score(kmin);
  float v = fexp(key_to_score(key) - smax);            // in (0, 1]
  u64 fix = (u64)fmaxf(1.0f, fmaf(v, FIXSCALE, 0.5f)); // clamp: SY can never be 0
  atomicAdd(&hist[g], (1ull << 46) | fix);             // peak bucket ~4 items: no contention
}

// ---------- 2) fused: scan + PAV + in-LDS merges + 2-level 8-way tree + out ----------
// 512 blocks x 256. Blocks 0-63 solve; blocks 64-511 are out-helpers that pre-gather
// cdf (gated by cdfrdy) and then wait for the root. Everyone writes 256 outputs.

__global__ __launch_bounds__(256) void solve_kernel(
    const u64* __restrict__ hist, u64* __restrict__ flags, u64* __restrict__ cdfrdy,
    u64* __restrict__ flag2, u64* __restrict__ grpf,
    u32* __restrict__ cdf, int2* __restrict__ REC,
    const u32* __restrict__ keyRaw, const u32* __restrict__ agg,
    float* __restrict__ out) {
  __shared__ u32 vals[BUCK_PER_BLK + 1];   // counts -> global-exclusive cdf
  __shared__ float seL[BUCK_PER_BLK];
  __shared__ int   rST[CH_PER_BLK * PAD];  // PAV stacks; later: out search table
  __shared__ float rSY[CH_PER_BLK * PAD];
  __shared__ u32 wsum[4];
  __shared__ u32 regS[65];                 // region start positions (global item idx)
  __shared__ int lcnt[CH_PER_BLK];
  __shared__ int ca[16], cb[16], cM[16];
  __shared__ int shInt[12];
  int t = threadIdx.x, b = blockIdx.x;
  u32 kmin = ~agg[0], kmax = agg[1];
  float smax = key_to_score(kmin);
  int oi = b * 256 + t;                    // this thread's single output item
  u32 okey = keyRaw[oi];
  u32 og = bucket_of(okey, kmin, kmax);
  float oexp = fexp(key_to_score(okey) - smax);
  int p_ = 0;

  if (b >= MBLK) {
    // ---- helper: wait for all 64 cdf publishes, pre-gather cdf (overlaps the tree) ----
    {
      u64 f;
      do {
        f = agent_ld(&cdfrdy[(size_t)(t & 63) * FPAD]);
        if (f == 0ull) __builtin_amdgcn_s_sleep(32);
      } while (f == 0ull);
    }
    __syncthreads();
    __threadfence();                       // acquire cdf
    p_ = (int)cdf[og];
  } else {
    // ---- phase 1: hist load + scan + global cdf ----
    int B0 = b * BUCK_PER_BLK;
    for (int q = 0; q < 8; ++q) {
      int ii = q * 256 + t;
      u64 acc = hist[(size_t)B0 + ii];
      vals[ii] = (u32)(acc >> 46);
      seL[ii] = (float)(acc & FIXMASK) * (1.0f / FIXSCALE);
    }
    __syncthreads();
    u32 loc[8]; u32 s = 0;
    for (int q = 0; q < 8; ++q) { loc[q] = s; s += vals[t * 8 + q]; }
    u32 inc = s;                           // wave-level inclusive scan (no barriers)
#pragma unroll
    for (int off = 1; off < 64; off <<= 1) {
      u32 o2 = (u32)__shfl_up((int)inc, off);
      if ((t & 63) >= off) inc += o2;
    }
    if ((t & 63) == 63) wsum[t >> 6] = inc;
    __syncthreads();
    u32 w = (u32)(t >> 6);
    u32 woff = 0;
    if (w > 0) woff += wsum[0];
    if (w > 1) woff += wsum[1];
    if (w > 2) woff += wsum[2];
    u32 total = wsum[0] + wsum[1] + wsum[2] + wsum[3];
    u32 texcl = woff + inc - s;
    // publish aggregate; wait-all over 64 solver blocks (load-only, padded slots)
    if (t == 0) atomicExch(&flags[(size_t)b * FPAD], (1ull << 32) | (u64)total);
    if (t < 64) {
      u64 f;
      do { f = agent_ld(&flags[(size_t)t * FPAD]); } while ((u32)(f >> 32) == 0u);
      u32 v = (u32)f, inc2 = v;
#pragma unroll
      for (int off = 1; off < 64; off <<= 1) {
        u32 o2 = (u32)__shfl_up((int)inc2, off);
        if (t >= off) inc2 += o2;
      }
      regS[t] = inc2 - v;
      if (t == 63) regS[64] = inc2;        // == N_ITEMS
    }
    __syncthreads();
    u32 exclu = regS[b];
    u32 tbase = texcl + exclu;
    u32 eb8[8];
    for (int q = 0; q < 8; ++q) { eb8[q] = tbase + loc[q]; vals[t * 8 + q] = eb8[q]; }
    {
      uint4* c4 = (uint4*)(cdf + B0 + t * 8);
      c4[0] = make_uint4(eb8[0], eb8[1], eb8[2], eb8[3]);
      c4[1] = make_uint4(eb8[4], eb8[5], eb8[6], eb8[7]);
    }
    if (t == 255) vals[BUCK_PER_BLK] = exclu + total;
    __syncthreads();                       // drains cdf stores
    if (t == 0) { __threadfence(); atomicExch(&cdfrdy[(size_t)b * FPAD], 1ull); }
    // ---- phase 2: per-chunk PAV (32 threads), stacks at padded stride ----
    if (t < CH_PER_BLK) {
      int base = t * PAD;
      int ptr = 0; bool have = false;
      float syT = 0.0f; int stT = 0;
      for (int k = 0; k < 64; ++k) {
        u32 cs = vals[t * 64 + k], ce = vals[t * 64 + k + 1];
        if (ce == cs) continue;                 // empty bucket
        float syC = seL[t * 64 + k];
        int stC = (int)cs, eC = (int)ce - 1;
        while (have) {
          float SWc = wsumf(stC, eC);
          float SWt = wsumf(stT, stC - 1);
          if (!(syT * SWc <= syC * SWt)) break; // merge while val_top <= val_cur
          syC += syT; stC = stT;
          if (ptr == 0) { have = false; break; }
          --ptr;
          stT = rST[base + ptr]; syT = rSY[base + ptr];
        }
        if (have) { rST[base + ptr] = stT; rSY[base + ptr] = syT; ++ptr; }
        stT = stC; syT = syC; have = true;
      }
      if (have) { rST[base + ptr] = stT; rSY[base + ptr] = syT; ++ptr; }
      lcnt[t] = ptr;
    }
    __syncthreads();
    // ---- phase 3: merge levels 0..4 in LDS; copies wave-parallel over disjoint pairs ----
    for (int j = 0; j < 5; ++j) {
      int P = CH_PER_BLK >> (j + 1);
      if (t < P) {
        int p = t;
        int kL = p << (j + 1), kR = kL + (1 << j);
        int slotL = kL * PAD, slotR = kR * PAD;
        int nL = lcnt[kL], nR = lcnt[kR];
        int a = 0, bb = 0, hasM = 0;
        if (nL > 0 && nR > 0) {
          int gstartR = (int)vals[kR * 64];
          int gendR   = (int)vals[(kR + (1 << j)) * 64];
          float SYL = rSY[slotL + nL - 1]; int stL = rST[slotL + nL - 1];
          float SYR = rSY[slotR];
          int eR = (nR > 1) ? (rST[slotR + 1] - 1) : (gendR - 1);
          float SWL = wsumf(stL, gstartR - 1);
          float SWR = wsumf(gstartR, eR);
          if (SYL * SWR <= SYR * SWL) {
            hasM = 1;
            float SYM = SYL + SYR; int Ms = stL, Me = eR;
            a = 1; bb = 1;
            for (;;) {
              float SWM = wsumf(Ms, Me);
              if (a < nL) {
                float SYe = rSY[slotL + nL - 1 - a]; int ste = rST[slotL + nL - 1 - a];
                float SWe = wsumf(ste, Ms - 1);
                if (SYe * SWM <= SYM * SWe) { SYM += SYe; Ms = ste; ++a; continue; }
              }
              if (bb < nR) {
                float SYb = rSY[slotR + bb]; int sb = rST[slotR + bb];
                int eb = (bb + 1 < nR) ? (rST[slotR + bb + 1] - 1) : (gendR - 1);
                float SWb = wsumf(sb, eb);
                if (SYM * SWb <= SYb * SWM) { SYM += SYb; Me = eb; ++bb; continue; }
              }
              break;
            }
            rST[slotL + nL - a] = Ms; rSY[slotL + nL - a] = SYM;
          }
        }
        ca[p] = a; cb[p] = bb; cM[p] = hasM;
      }
      __syncthreads();
      {
        int wv = t >> 6, lane = t & 63;
        for (int p = wv; p < P; p += 4) {      // pairs disjoint -> waves in parallel
          int kL = p << (j + 1), kR = kL + (1 << j);
          int nL = lcnt[kL], nR = lcnt[kR];
          int a = ca[p], bb = cb[p], hasM = cM[p];
          int destBase = kL * PAD + nL - a + hasM;
          int srcBase = kR * PAD + bb;
          int ncopy = nR - bb;
          for (int off = 0; off < ncopy; off += 64) {  // wave-staged, dest<=src, in order
            int k2 = off + lane; bool act = k2 < ncopy;
            int vt = 0; float vs = 0.f;
            if (act) { vt = rST[srcBase + k2]; vs = rSY[srcBase + k2]; }
            if (act) { rST[destBase + k2] = vt; rSY[destBase + k2] = vs; }
          }
        }
      }
      __syncthreads();
      if (t < P) {
        int p = t; int kL = p << (j + 1), kR = kL + (1 << j);
        lcnt[kL] = lcnt[kL] - ca[p] + cM[p] + (lcnt[kR] - cb[p]);
      }
      __syncthreads();
    }
    // ---- publish region stack ----
    int myCnt = lcnt[0];
    for (int k = t; k < myCnt; k += 256)
      REC[(size_t)b * REGSLOT + k] = make_int2(rST[k], __float_as_int(rSY[k]));
    __syncthreads();
    if (t == 0) { __threadfence(); atomicExch(&flag2[(size_t)b * FPAD], (1ull << 32) | (u64)(u32)myCnt); }
    // ---- level 1: leaders (b%8==0) 8-way merge regions b..b+7; ONE fence round-trip ----
    if ((b & 7) == 0) {
      if (t < 7) {
        u64 f;
        do { f = agent_ld(&flag2[(size_t)(b + 1 + t) * FPAD]); } while ((u32)(f >> 32) == 0u);
        shInt[4 + t] = (int)(u32)f;
      }
      __syncthreads();
      __threadfence();                     // acquire all 7 partner stacks
      int nL = myCnt;
      int slotL = b * REGSLOT;
      for (int k = 1; k < 8; ++k) {
        int nR = shInt[4 + k - 1];
        int slotR = (b + k) * REGSLOT;
        int gstartR = (int)regS[b + k];
        int gendR   = (int)regS[b + k + 1];
        if (t == 0) {
          int a = 0, bb = 0, hasM = 0;
          if (nL > 0 && nR > 0) {
            int2 rL = REC[slotL + nL - 1];
            float SYL = recSY(rL); int stL = rL.x;
            int2 rR = REC[slotR];
            float SYR = recSY(rR);
            int eR = (nR > 1) ? (REC[slotR + 1].x - 1) : (gendR - 1);
            float SWL = wsumf(stL, gstartR - 1);
            float SWR = wsumf(gstartR, eR);
            if (SYL * SWR <= SYR * SWL) {
              hasM = 1;
              float SYM = SYL + SYR; int Ms = stL, Me = eR;
              a = 1; bb = 1;
              for (;;) {
                float SWM = wsumf(Ms, Me);
                if (a < nL) {
                  int2 re = REC[slotL + nL - 1 - a];
                  float SYe = recSY(re); int ste = re.x;
                  float SWe = wsumf(ste, Ms - 1);
                  if (SYe * SWM <= SYM * SWe) { SYM += SYe; Ms = ste; ++a; continue; }
                }
                if (bb < nR) {
                  int2 rb = REC[slotR + bb];
                  float SYb = recSY(rb); int sb = rb.x;
                  int eb = (bb + 1 < nR) ? (REC[slotR + bb + 1].x - 1) : (gendR - 1);
                  float SWb = wsumf(sb, eb);
                  if (SYM * SWb <= SYb * SWM) { SYM += SYb; Me = eb; ++bb; continue; }
                }
                break;
              }
              REC[slotL + nL - a] = make_int2(Ms, __float_as_int(SYM));
            }
          }
          shInt[0] = a; shInt[1] = bb; shInt[2] = hasM;
        }
        __syncthreads();
        int a = shInt[0], bb = shInt[1], hasM = shInt[2];
        int destBase = slotL + nL - a + hasM;
        int srcBase = slotR + bb;
        int ncopy = nR - bb;
        for (int k2 = t; k2 < ncopy; k2 += 256) REC[destBase + k2] = REC[srcBase + k2];
        nL = nL - a + hasM + ncopy;        // prefix-sum bound keeps dest < slot of region b+k+1
        __syncthreads();
      }
      myCnt = nL;
      if (t == 0) { __threadfence(); atomicExch(&grpf[(size_t)(b >> 3) * FPAD], (1ull << 32) | (u64)(u32)myCnt); }
    }
    // ---- level 2: block 0 8-way merges the 8 group stacks; ONE fence round-trip ----
    if (b == 0) {
      if (t < 7) {
        u64 f;
        do { f = agent_ld(&grpf[(size_t)(1 + t) * FPAD]); } while ((u32)(f >> 32) == 0u);
        shInt[4 + t] = (int)(u32)f;
      }
      __syncthreads();
      __threadfence();
      int nL = myCnt;
      int slotL = 0;
      for (int k = 1; k < 8; ++k) {
        int nR = shInt[4 + k - 1];
        int slotR = (k * 8) * REGSLOT;
        int gstartR = (int)regS[k * 8];
        int gendR   = (int)regS[k * 8 + 8];
        if (t == 0) {
          int a = 0, bb = 0, hasM = 0;
          if (nL > 0 && nR > 0) {
            int2 rL = REC[slotL + nL - 1];
            float SYL = recSY(rL); int stL = rL.x;
            int2 rR = REC[slotR];
            float SYR = recSY(rR);
            int eR = (nR > 1) ? (REC[slotR + 1].x - 1) : (gendR - 1);
            float SWL = wsumf(stL, gstartR - 1);
            float SWR = wsumf(gstartR, eR);
            if (SYL * SWR <= SYR * SWL) {
              hasM = 1;
              float SYM = SYL + SYR; int Ms = stL, Me = eR;
              a = 1; bb = 1;
              for (;;) {
                float SWM = wsumf(Ms, Me);
                if (a < nL) {
                  int2 re = REC[slotL + nL - 1 - a];
                  float SYe = recSY(re); int ste = re.x;
                  float SWe = wsumf(ste, Ms - 1);
                  if (SYe * SWM <= SYM * SWe) { SYM += SYe; Ms = ste; ++a; continue; }
                }
                if (bb < nR) {
                  int2 rb = REC[slotR + bb];
                  float SYb = recSY(rb); int sb = rb.x;
                  int eb = (bb + 1 < nR) ? (REC[slotR + bb + 1].x - 1) : (gendR - 1);
                  float SWb = wsumf(sb, eb);
                  if (SYM * SWb <= SYb * SWM) { SYM += SYb; Me = eb; ++bb; continue; }
                }
                break;
              }
              REC[slotL + nL - a] = make_int2(Ms, __float_as_int(SYM));
            }
          }
          shInt[0] = a; shInt[1] = bb; shInt[2] = hasM;
        }
        __syncthreads();
        int a = shInt[0], bb = shInt[1], hasM = shInt[2];
        int destBase = slotL + nL - a + hasM;
        int srcBase = slotR + bb;
        int ncopy = nR - bb;
        for (int k2 = t; k2 < ncopy; k2 += 256) REC[destBase + k2] = REC[srcBase + k2];
        nL = nL - a + hasM + ncopy;
        __syncthreads();
      }
      if (t == 0) { __threadfence(); atomicExch(&grpf[(size_t)8 * FPAD], (2ull << 32) | (u64)(u32)nL); }
    }
  }

  // ---- common out phase: poll root, stage record table, search, write 1 item/thread ----
  if (t == 0) {
    u64 f;
    do {
      f = agent_ld(&grpf[(size_t)8 * FPAD]);
      if ((f >> 32) != 2ull) __builtin_amdgcn_s_sleep(2);
    } while ((f >> 32) != 2ull);
    shInt[0] = (int)(u32)f;
  }
  __syncthreads();
  __threadfence();                         // acquire final REC (+ cdf for solver blocks)
  int m = shInt[0];
  if (b < MBLK) p_ = (int)cdf[og];
  bool useL = (m <= CH_PER_BLK * PAD);
  if (useL) {
    for (int k = t; k < m; k += 256) {
      int2 r = REC[k];
      rST[k] = r.x; rSY[k] = __int_as_float(r.y);
    }
  }
  __syncthreads();
  int lo = 0, hi = m - 1;
  if (useL) {
    while (lo < hi) {
      int mid = (lo + hi + 1) >> 1;
      if (rST[mid] <= p_) lo = mid; else hi = mid - 1;
    }
    int s0 = rST[lo];
    int e0 = (lo + 1 < m) ? (rST[lo + 1] - 1) : (N_ITEMS - 1);
    float SW = wsumf(s0, e0);
    float rank = oexp * SW / rSY[lo];
    out[oi] = floorf(rank * (1.0f / 3.0f)) + 1.0f;
  } else {
    while (lo < hi) {
      int mid = (lo + hi + 1) >> 1;
      if (REC[mid].x <= p_) lo = mid; else hi = mid - 1;
    }
    int2 r = REC[lo];
    int s0 = r.x;
    int e0 = (lo + 1 < m) ? (REC[lo + 1].x - 1) : (N_ITEMS - 1);
    float SW = wsumf(s0, e0);
    float rank = oexp * SW / recSY(r);
    out[oi] = floorf(rank * (1.0f / 3.0f)) + 1.0f;
  }
}

// ---------- launch ----------

extern "C" void kernel_launch(void* const* d_in, const int* in_sizes, int n_in,
                              void* d_out, int out_size, void* d_ws, size_t ws_size,
                              hipStream_t stream) {
  const float* x  = (const float*)d_in[0];
  const float* w1 = (const float*)d_in[1];
  const float* b1 = (const float*)d_in[2];
  const float* w2 = (const float*)d_in[3];
  const float* b2 = (const float*)d_in[4];
  float* out = (float*)d_out;

  char* ws = (char*)d_ws;
  size_t o = 0;
  u32* cdf    = (u32*)(ws + o); o += (size_t)(NB + 4) * 4;
  u32* keyRaw = (u32*)(ws + o); o += (size_t)N_ITEMS * 4;
  int2* REC   = (int2*)(ws + o); o += (size_t)N_ITEMS * 8;
  u64* hist   = (u64*)(ws + o); o += (size_t)NB * 8;             // 1 MB, zeroed in-kernel
  // ---- zero-initialized control region (one small memset: ~90 KB) ----
  char* zbase = ws + o;
  u64* bar    = (u64*)(ws + o); o += (size_t)NBLK * FPAD * 8;    // 512 padded arrive flags
  u64* rel    = (u64*)(ws + o); o += (size_t)FPAD * 8;           // release flag
  u64* flags  = (u64*)(ws + o); o += (size_t)MBLK * FPAD * 8;    // aggregate publish
  u64* cdfrdy = (u64*)(ws + o); o += (size_t)MBLK * FPAD * 8;    // cdf-ready publish
  u64* flag2  = (u64*)(ws + o); o += (size_t)MBLK * FPAD * 8;    // region stack publish
  u64* grpf   = (u64*)(ws + o); o += (size_t)9 * FPAD * 8;       // 8 group flags + root
  u32* agg    = (u32*)(ws + o); o += 64;
  size_t zbytes = (size_t)((ws + o) - zbase);

  hipMemsetAsync(zbase, 0, zbytes, stream);
  score_hist_kernel<<<NBLK, 256, 0, stream>>>(x, w1, b1, w2, b2, keyRaw, agg, hist, bar, rel);
  solve_kernel<<<NBLK, 256, 0, stream>>>(hist, flags, cdfrdy, flag2, grpf,
                                         cdf, REC, keyRaw, agg, out);
}

// Round 5
// 116.847 us; speedup vs baseline: 1.7787x; 1.7787x over previous
//
#include <hip/hip_runtime.h>
#include <stdint.h>

typedef unsigned int u32;
typedef unsigned long long u64;

#define N_ITEMS 131072
#define NB 131072                   // buckets (monotone in descending score)
#define NSLICE 4                    // XCD-sliced histogram copies
#define MBLK 64                     // solver blocks
#define BUCK_PER_BLK 2048           // buckets per solver block
#define CH_PER_BLK 32               // chunks (64 buckets) per solver block
#define PAD 65                      // padded LDS record stride per chunk
#define REGSLOT 2048                // record slots per region in global REC
#define FPAD 16                     // u64s per flag slot -> 128B (own cacheline)
#define FIXSCALE 268435456.0f       // 2^28 fixed-point scale for sum(exp)
#define FIXMASK ((1ull << 46) - 1)

// ---------- helpers ----------

// sum_{i=s}^{e} (N - i) — exact weight-side sum of exp(w) over sorted positions
__device__ __forceinline__ float wsumf(int s, int e) {
  return 0.5f * (float)(e - s + 1) * (float)(2 * N_ITEMS - s - e);
}

__device__ __forceinline__ float key_to_score(u32 key) {
  u32 m = ~key;
  u32 u = (m & 0x80000000u) ? (m ^ 0x80000000u) : ~m;
  return __uint_as_float(u);
}

#define LOG2E 1.4426950408889634f
__device__ __forceinline__ float fexp(float x) { return exp2f(x * LOG2E); }

// ascending key == descending score; ascending bucket == descending score
__device__ __forceinline__ u32 bucket_of(u32 key, u32 kmin, u32 kmax) {
  double scale = (double)NB / ((double)(kmax - kmin) + 1.0);
  u32 b = (u32)((double)(key - kmin) * scale);
  return b < NB ? b : (NB - 1);
}

__device__ __forceinline__ float recSY(int2 r) { return __int_as_float(r.y); }

// relaxed agent-scope load: polls WITHOUT taking exclusive line ownership
__device__ __forceinline__ u64 agent_ld(const u64* p) {
  return __hip_atomic_load(p, __ATOMIC_RELAXED, __HIP_MEMORY_SCOPE_AGENT);
}

// one pairwise region-merge step: t0 walks the cascade, 256 threads do the
// staged compaction copy (register-batched 2048/stage; dest<=src keeps stages safe).
// Returns the merged count. All arguments wave-uniform.
__device__ int merge_step(int2* __restrict__ REC, int slotL, int nL,
                          int slotR, int nR, int gstartR, int gendR,
                          int t, int* shInt) {
  if (t == 0) {
    int a = 0, bb = 0, hasM = 0;
    if (nL > 0 && nR > 0) {
      int2 rL = REC[slotL + nL - 1];
      float SYL = recSY(rL); int stL = rL.x;
      int2 rR = REC[slotR];
      float SYR = recSY(rR);
      int eR = (nR > 1) ? (REC[slotR + 1].x - 1) : (gendR - 1);
      float SWL = wsumf(stL, gstartR - 1);
      float SWR = wsumf(gstartR, eR);
      if (SYL * SWR <= SYR * SWL) {
        hasM = 1;
        float SYM = SYL + SYR; int Ms = stL, Me = eR;
        a = 1; bb = 1;
        for (;;) {
          float SWM = wsumf(Ms, Me);
          if (a < nL) {
            int2 re = REC[slotL + nL - 1 - a];
            float SYe = recSY(re); int ste = re.x;
            float SWe = wsumf(ste, Ms - 1);
            if (SYe * SWM <= SYM * SWe) { SYM += SYe; Ms = ste; ++a; continue; }
          }
          if (bb < nR) {
            int2 rb = REC[slotR + bb];
            float SYb = recSY(rb); int sb = rb.x;
            int eb = (bb + 1 < nR) ? (REC[slotR + bb + 1].x - 1) : (gendR - 1);
            float SWb = wsumf(sb, eb);
            if (SYM * SWb <= SYb * SWM) { SYM += SYb; Me = eb; ++bb; continue; }
          }
          break;
        }
        REC[slotL + nL - a] = make_int2(Ms, __float_as_int(SYM));
      }
    }
    shInt[0] = a; shInt[1] = bb; shInt[2] = hasM;
  }
  __syncthreads();
  int a = shInt[0], bb = shInt[1], hasM = shInt[2];
  int destBase = slotL + nL - a + hasM;
  int srcBase = slotR + bb;
  int ncopy = nR - bb;
  if (destBase != srcBase) {
    for (int off = 0; off < ncopy; off += 2048) {
      int2 v[8];
#pragma unroll
      for (int j = 0; j < 8; ++j) {
        int k2 = off + j * 256 + t;
        if (k2 < ncopy) v[j] = REC[srcBase + k2];
      }
      __syncthreads();
#pragma unroll
      for (int j = 0; j < 8; ++j) {
        int k2 = off + j * 256 + t;
        if (k2 < ncopy) REC[destBase + k2] = v[j];
      }
      __syncthreads();
    }
  }
  __syncthreads();
  return nL - a + hasM + ncopy;
}

// ---------- 1) scores -> keys; per-block minmax; zero hist/flags ----------

__global__ __launch_bounds__(256) void score_key_kernel(
    const float* __restrict__ x,
    const float* __restrict__ w1, const float* __restrict__ b1,
    const float* __restrict__ w2, const float* __restrict__ b2,
    u32* __restrict__ keyRaw, u32* __restrict__ pmin, u32* __restrict__ pmax,
    u64* __restrict__ hist8, u64* __restrict__ flags, u64* __restrict__ grpf) {
  __shared__ u32 wmn[4], wmx[4];
  int t = threadIdx.x;
  int i = blockIdx.x * 256 + t;
  // zero the 4 MB sliced histogram (2 x uint4 per thread, coalesced)
  uint4 z = make_uint4(0u, 0u, 0u, 0u);
  ((uint4*)hist8)[i] = z;
  ((uint4*)hist8)[i + N_ITEMS] = z;
  if (i < MBLK) flags[(size_t)i * FPAD] = 0ull;
  if (i < 9) grpf[(size_t)i * FPAD] = 0ull;
  float xv = x[i];
  float s = b2[0];
#pragma unroll
  for (int j = 0; j < 32; ++j) {
    float h = fmaf(xv, w1[j], b1[j]);
    h = fmaxf(h, 0.0f);
    s = fmaf(h, w2[j], s);
  }
  u32 u = __float_as_uint(s);
  u32 m = u ^ ((u & 0x80000000u) ? 0xFFFFFFFFu : 0x80000000u); // ascending map
  u32 key = ~m;
  keyRaw[i] = key;
  u32 mn = key, mx = key;
#pragma unroll
  for (int off = 32; off > 0; off >>= 1) {
    mn = min(mn, (u32)__shfl_xor((int)mn, off));
    mx = max(mx, (u32)__shfl_xor((int)mx, off));
  }
  if ((t & 63) == 0) { wmn[t >> 6] = mn; wmx[t >> 6] = mx; }
  __syncthreads();
  if (t == 0) {
    mn = min(min(wmn[0], wmn[1]), min(wmn[2], wmn[3]));
    mx = max(max(wmx[0], wmx[1]), max(wmx[2], wmx[3]));
    pmin[blockIdx.x] = mn;
    pmax[blockIdx.x] = mx;
  }
}

// ---------- 2) bucket aggregates: ONE packed u64 atomic per item, XCD-sliced ----------
// bits [46:63] = count, bits [0:45] = fixed-point (2^28) sum of exp(s - smax)

__global__ __launch_bounds__(256) void hist_kernel(
    const u32* __restrict__ keyRaw,
    const u32* __restrict__ pmin, const u32* __restrict__ pmax,
    u64* __restrict__ hist8, u32* __restrict__ mm) {
  __shared__ u32 s0[256], s1[256];
  int t = threadIdx.x;
  s0[t] = min(pmin[t], pmin[t + 256]);
  s1[t] = max(pmax[t], pmax[t + 256]);
  __syncthreads();
  for (int off = 128; off > 0; off >>= 1) {
    if (t < off) { s0[t] = min(s0[t], s0[t + off]); s1[t] = max(s1[t], s1[t + off]); }
    __syncthreads();
  }
  u32 kmin = s0[0], kmax = s1[0];
  if (blockIdx.x == 0 && t == 0) { mm[0] = kmin; mm[1] = kmax; }
  int i = blockIdx.x * 256 + t;
  u32 key = keyRaw[i];
  u32 g = bucket_of(key, kmin, kmax);
  float smax = key_to_score(kmin);
  float v = fexp(key_to_score(key) - smax);            // in (0, 1]
  u64 fix = (u64)fmaxf(1.0f, fmaf(v, FIXSCALE, 0.5f)); // clamp: SY can never be 0
  size_t slice = (size_t)(blockIdx.x & (NSLICE - 1)) * NB;
  atomicAdd(&hist8[slice + g], (1ull << 46) | fix);
}

// ---------- 3) scan + PAV + in-LDS merges -> 64 region stacks ----------

__global__ __launch_bounds__(256) void scan_pav_kernel(
    const u64* __restrict__ hist8, u64* __restrict__ flags,
    u32* __restrict__ cdf, int2* __restrict__ REC,
    int* __restrict__ cnt2, u32* __restrict__ rstart) {
  __shared__ u32 vals[BUCK_PER_BLK + 1];   // counts -> global-exclusive cdf
  __shared__ float seL[BUCK_PER_BLK];
  __shared__ int   rST[CH_PER_BLK * PAD];
  __shared__ float rSY[CH_PER_BLK * PAD];
  __shared__ u32 wsum[4];
  __shared__ u32 regS[65];
  __shared__ int lcnt[CH_PER_BLK];
  __shared__ int ca[16], cb[16], cM[16];
  int t = threadIdx.x, b = blockIdx.x;
  int B0 = b * BUCK_PER_BLK;
  // coalesced load + slice reduce
  for (int q = 0; q < 8; ++q) {
    int ii = q * 256 + t;
    u64 acc = 0;
#pragma unroll
    for (int c = 0; c < NSLICE; ++c) acc += hist8[(size_t)c * NB + B0 + ii];
    vals[ii] = (u32)(acc >> 46);
    seL[ii] = (float)(acc & FIXMASK) * (1.0f / FIXSCALE);
  }
  __syncthreads();
  // per-thread local prefix over contiguous 8, then wave shfl scan + 4-wave combine
  u32 loc[8]; u32 s = 0;
  for (int q = 0; q < 8; ++q) { loc[q] = s; s += vals[t * 8 + q]; }
  u32 inc = s;
#pragma unroll
  for (int off = 1; off < 64; off <<= 1) {
    u32 o2 = (u32)__shfl_up((int)inc, off);
    if ((t & 63) >= off) inc += o2;
  }
  if ((t & 63) == 63) wsum[t >> 6] = inc;
  __syncthreads();
  u32 w = (u32)(t >> 6);
  u32 woff = 0;
  if (w > 0) woff += wsum[0];
  if (w > 1) woff += wsum[1];
  if (w > 2) woff += wsum[2];
  u32 total = wsum[0] + wsum[1] + wsum[2] + wsum[3];
  u32 texcl = woff + inc - s;
  // publish aggregate; wait-all over 64 blocks (64 distinct lines, 64 pollers: safe)
  if (t == 0) atomicExch(&flags[(size_t)b * FPAD], (1ull << 32) | (u64)total);
  if (t < 64) {
    u64 f;
    do { f = agent_ld(&flags[(size_t)t * FPAD]); } while ((u32)(f >> 32) == 0u);
    u32 v = (u32)f, inc2 = v;
#pragma unroll
    for (int off = 1; off < 64; off <<= 1) {
      u32 o2 = (u32)__shfl_up((int)inc2, off);
      if (t >= off) inc2 += o2;
    }
    regS[t] = inc2 - v;
    if (t == 63) regS[64] = inc2;          // == N_ITEMS
  }
  __syncthreads();
  u32 exclu = regS[b];
  u32 tbase = texcl + exclu;
  // overwrite vals with GLOBAL exclusive cdf; mirror to global (vectorized)
  u32 eb8[8];
  for (int q = 0; q < 8; ++q) { eb8[q] = tbase + loc[q]; vals[t * 8 + q] = eb8[q]; }
  {
    uint4* c4 = (uint4*)(cdf + B0 + t * 8);
    c4[0] = make_uint4(eb8[0], eb8[1], eb8[2], eb8[3]);
    c4[1] = make_uint4(eb8[4], eb8[5], eb8[6], eb8[7]);
  }
  if (t == 255) vals[BUCK_PER_BLK] = exclu + total;
  if (b == 0 && t < 65) rstart[t] = regS[t];
  __syncthreads();
  // per-chunk PAV (32 threads), stack stored in place at padded stride
  if (t < CH_PER_BLK) {
    int base = t * PAD;
    int ptr = 0; bool have = false;
    float syT = 0.0f; int stT = 0;
    for (int k = 0; k < 64; ++k) {
      u32 cs = vals[t * 64 + k], ce = vals[t * 64 + k + 1];
      if (ce == cs) continue;                 // empty bucket
      float syC = seL[t * 64 + k];
      int stC = (int)cs, eC = (int)ce - 1;
      while (have) {
        float SWc = wsumf(stC, eC);
        float SWt = wsumf(stT, stC - 1);
        if (!(syT * SWc <= syC * SWt)) break; // merge while val_top <= val_cur
        syC += syT; stC = stT;
        if (ptr == 0) { have = false; break; }
        --ptr;
        stT = rST[base + ptr]; syT = rSY[base + ptr];
      }
      if (have) { rST[base + ptr] = stT; rSY[base + ptr] = syT; ++ptr; }
      stT = stC; syT = syC; have = true;
    }
    if (have) { rST[base + ptr] = stT; rSY[base + ptr] = syT; ++ptr; }
    lcnt[t] = ptr;
  }
  __syncthreads();
  // merge levels 0..4 entirely in LDS; copies wave-parallel across disjoint pairs
  for (int j = 0; j < 5; ++j) {
    int P = CH_PER_BLK >> (j + 1);
    if (t < P) {
      int p = t;
      int kL = p << (j + 1), kR = kL + (1 << j);
      int slotL = kL * PAD, slotR = kR * PAD;
      int nL = lcnt[kL], nR = lcnt[kR];
      int a = 0, bb = 0, hasM = 0;
      if (nL > 0 && nR > 0) {
        int gstartR = (int)vals[kR * 64];
        int gendR   = (int)vals[(kR + (1 << j)) * 64];
        float SYL = rSY[slotL + nL - 1]; int stL = rST[slotL + nL - 1];
        float SYR = rSY[slotR];
        int eR = (nR > 1) ? (rST[slotR + 1] - 1) : (gendR - 1);
        float SWL = wsumf(stL, gstartR - 1);
        float SWR = wsumf(gstartR, eR);
        if (SYL * SWR <= SYR * SWL) {
          hasM = 1;
          float SYM = SYL + SYR; int Ms = stL, Me = eR;
          a = 1; bb = 1;
          for (;;) {
            float SWM = wsumf(Ms, Me);
            if (a < nL) {
              float SYe = rSY[slotL + nL - 1 - a]; int ste = rST[slotL + nL - 1 - a];
              float SWe = wsumf(ste, Ms - 1);
              if (SYe * SWM <= SYM * SWe) { SYM += SYe; Ms = ste; ++a; continue; }
            }
            if (bb < nR) {
              float SYb = rSY[slotR + bb]; int sb = rST[slotR + bb];
              int eb = (bb + 1 < nR) ? (rST[slotR + bb + 1] - 1) : (gendR - 1);
              float SWb = wsumf(sb, eb);
              if (SYM * SWb <= SYb * SWM) { SYM += SYb; Me = eb; ++bb; continue; }
            }
            break;
          }
          rST[slotL + nL - a] = Ms; rSY[slotL + nL - a] = SYM;
        }
      }
      ca[p] = a; cb[p] = bb; cM[p] = hasM;
    }
    __syncthreads();
    {
      int wv = t >> 6, lane = t & 63;
      for (int p = wv; p < P; p += 4) {      // pairs disjoint -> waves in parallel
        int kL = p << (j + 1), kR = kL + (1 << j);
        int nL = lcnt[kL], nR = lcnt[kR];
        int a = ca[p], bb = cb[p], hasM = cM[p];
        int destBase = kL * PAD + nL - a + hasM;
        int srcBase = kR * PAD + bb;
        int ncopy = nR - bb;
        for (int off = 0; off < ncopy; off += 64) {  // wave-staged, dest<=src, in order
          int k2 = off + lane; bool act = k2 < ncopy;
          int vt = 0; float vs = 0.f;
          if (act) { vt = rST[srcBase + k2]; vs = rSY[srcBase + k2]; }
          if (act) { rST[destBase + k2] = vt; rSY[destBase + k2] = vs; }
        }
      }
    }
    __syncthreads();
    if (t < P) {
      int p = t; int kL = p << (j + 1), kR = kL + (1 << j);
      lcnt[kL] = lcnt[kL] - ca[p] + cM[p] + (lcnt[kR] - cb[p]);
    }
    __syncthreads();
  }
  // write region records (coalesced) + count
  int n = lcnt[0];
  for (int k = t; k < n; k += 256)
    REC[(size_t)b * REGSLOT + k] = make_int2(rST[k], __float_as_int(rSY[k]));
  if (t == 0) cnt2[b] = n;
}

// ---------- 4) single merge kernel: 8 blocks x (8-way in-group), block 0 finishes ----------

__global__ __launch_bounds__(256) void merge_kernel(
    int2* __restrict__ REC, int* __restrict__ cnt2,
    const u32* __restrict__ rstart, u64* __restrict__ grpf) {
  __shared__ int shInt[4];
  __shared__ int gcnt[8];
  __shared__ u32 rs[65];
  __shared__ int pcnt[8];
  int t = threadIdx.x, b = blockIdx.x;
  if (t < 8) gcnt[t] = cnt2[b * 8 + t];
  if (t < 65) rs[t] = rstart[t];
  __syncthreads();
  int nL = gcnt[0];
  int slotL = (b * 8) * REGSLOT;
  for (int k = 1; k < 8; ++k) {
    int nR = gcnt[k];
    int slotR = (b * 8 + k) * REGSLOT;
    nL = merge_step(REC, slotL, nL, slotR, nR,
                    (int)rs[b * 8 + k], (int)rs[b * 8 + k + 1], t, shInt);
  }
  if (t == 0) { __threadfence(); atomicExch(&grpf[(size_t)b * FPAD], (1ull << 32) | (u64)(u32)nL); }
  if (b == 0) {
    // 7 distinct lines, one poller each: safe pattern
    if (t < 7) {
      u64 f;
      do { f = agent_ld(&grpf[(size_t)(1 + t) * FPAD]); } while ((u32)(f >> 32) == 0u);
      pcnt[1 + t] = (int)(u32)f;
    }
    __syncthreads();
    __threadfence();                       // acquire the 7 group stacks
    for (int k = 1; k < 8; ++k) {
      int nR = pcnt[k];
      int slotR = (k * 8) * REGSLOT;
      nL = merge_step(REC, 0, nL, slotR, nR,
                      (int)rs[k * 8], (int)rs[k * 8 + 8], t, shInt);
    }
    if (t == 0) cnt2[0] = nL;              // kernel boundary publishes to out_kernel
  }
}

// ---------- 5) ranks + transform; LDS-staged search table; coalesced output ----------

__global__ __launch_bounds__(256) void out_kernel(
    const u32* __restrict__ keyRaw, const u32* __restrict__ mm,
    const u32* __restrict__ cdf, const int2* __restrict__ REC,
    const int* __restrict__ cnt2, float* __restrict__ out) {
  __shared__ int   rST[CH_PER_BLK * PAD];
  __shared__ float rSY[CH_PER_BLK * PAD];
  int t = threadIdx.x;
  int i = blockIdx.x * 256 + t;
  int m = cnt2[0];
  u32 kmin = mm[0], kmax = mm[1];
  u32 key = keyRaw[i];
  float smax = key_to_score(kmin);
  u32 g = bucket_of(key, kmin, kmax);
  int p = (int)cdf[g];               // block is bucket-aligned: position of bucket start
  bool useL = (m <= CH_PER_BLK * PAD);
  if (useL) {
    for (int k = t; k < m; k += 256) {
      int2 r = REC[k];
      rST[k] = r.x; rSY[k] = __int_as_float(r.y);
    }
  }
  __syncthreads();
  int lo = 0, hi = m - 1;
  if (useL) {
    while (lo < hi) {
      int mid = (lo + hi + 1) >> 1;
      if (rST[mid] <= p) lo = mid; else hi = mid - 1;
    }
    int s0 = rST[lo];
    int e0 = (lo + 1 < m) ? (rST[lo + 1] - 1) : (N_ITEMS - 1);
    float SW = wsumf(s0, e0);
    float rank = fexp(key_to_score(key) - smax) * SW / rSY[lo];
    out[i] = floorf(rank * (1.0f / 3.0f)) + 1.0f;
  } else {
    while (lo < hi) {
      int mid = (lo + hi + 1) >> 1;
      if (REC[mid].x <= p) lo = mid; else hi = mid - 1;
    }
    int2 r = REC[lo];
    int s0 = r.x;
    int e0 = (lo + 1 < m) ? (REC[lo + 1].x - 1) : (N_ITEMS - 1);
    float SW = wsumf(s0, e0);
    float rank = fexp(key_to_score(key) - smax) * SW / recSY(r);
    out[i] = floorf(rank * (1.0f / 3.0f)) + 1.0f;
  }
}

// ---------- launch ----------

extern "C" void kernel_launch(void* const* d_in, const int* in_sizes, int n_in,
                              void* d_out, int out_size, void* d_ws, size_t ws_size,
                              hipStream_t stream) {
  const float* x  = (const float*)d_in[0];
  const float* w1 = (const float*)d_in[1];
  const float* b1 = (const float*)d_in[2];
  const float* w2 = (const float*)d_in[3];
  const float* b2 = (const float*)d_in[4];
  float* out = (float*)d_out;

  char* ws = (char*)d_ws;
  size_t o = 0;
  u32* mm     = (u32*)(ws + o); o += 64;
  u32* pmin   = (u32*)(ws + o); o += (size_t)512 * 4;
  u32* pmax   = (u32*)(ws + o); o += (size_t)512 * 4;
  u32* cdf    = (u32*)(ws + o); o += (size_t)(NB + 4) * 4;
  u32* rstart = (u32*)(ws + o); o += (size_t)(MBLK + 4) * 4;
  u32* keyRaw = (u32*)(ws + o); o += (size_t)N_ITEMS * 4;
  int2* REC   = (int2*)(ws + o); o += (size_t)N_ITEMS * 8;
  int* cnt2   = (int*)(ws + o);  o += (size_t)MBLK * 4;
  u64* hist8  = (u64*)(ws + o); o += (size_t)NSLICE * NB * 8;    // 4 MB, zeroed in k1
  u64* flags  = (u64*)(ws + o); o += (size_t)MBLK * FPAD * 8;    // zeroed in k1
  u64* grpf   = (u64*)(ws + o); o += (size_t)9 * FPAD * 8;       // zeroed in k1

  score_key_kernel<<<512, 256, 0, stream>>>(x, w1, b1, w2, b2, keyRaw,
                                            pmin, pmax, hist8, flags, grpf);
  hist_kernel<<<512, 256, 0, stream>>>(keyRaw, pmin, pmax, hist8, mm);
  scan_pav_kernel<<<MBLK, 256, 0, stream>>>(hist8, flags, cdf, REC, cnt2, rstart);
  merge_kernel<<<8, 256, 0, stream>>>(REC, cnt2, rstart, grpf);
  out_kernel<<<512, 256, 0, stream>>>(keyRaw, mm, cdf, REC, cnt2, out);
}